// Round 5
// baseline (765.761 us; speedup 1.0000x reference)
//
#include <hip/hip_runtime.h>
#include <math.h>
#include <limits.h>

#define M_ROWS 65536   // B*N = 64*1024
#define DD     256     // feature dim
#define KC     512     // codes

// numpy-style pairwise sum (8 accumulators, block 128) of squares of 128 floats.
__device__ __forceinline__ float pw128_sq(const float4* __restrict__ q) {
  float r[8];
  {
    float4 a = q[0], b = q[1];
    r[0] = __fmul_rn(a.x, a.x); r[1] = __fmul_rn(a.y, a.y);
    r[2] = __fmul_rn(a.z, a.z); r[3] = __fmul_rn(a.w, a.w);
    r[4] = __fmul_rn(b.x, b.x); r[5] = __fmul_rn(b.y, b.y);
    r[6] = __fmul_rn(b.z, b.z); r[7] = __fmul_rn(b.w, b.w);
  }
#pragma unroll
  for (int i = 2; i < 32; i += 2) {
    float4 a = q[i], b = q[i + 1];
    r[0] = __fadd_rn(r[0], __fmul_rn(a.x, a.x));
    r[1] = __fadd_rn(r[1], __fmul_rn(a.y, a.y));
    r[2] = __fadd_rn(r[2], __fmul_rn(a.z, a.z));
    r[3] = __fadd_rn(r[3], __fmul_rn(a.w, a.w));
    r[4] = __fadd_rn(r[4], __fmul_rn(b.x, b.x));
    r[5] = __fadd_rn(r[5], __fmul_rn(b.y, b.y));
    r[6] = __fadd_rn(r[6], __fmul_rn(b.z, b.z));
    r[7] = __fadd_rn(r[7], __fmul_rn(b.w, b.w));
  }
  return __fadd_rn(__fadd_rn(__fadd_rn(r[0], r[1]), __fadd_rn(r[2], r[3])),
                   __fadd_rn(__fadd_rn(r[4], r[5]), __fadd_rn(r[6], r[7])));
}

__global__ void sumsq_kernel(const float* __restrict__ x, float* __restrict__ s,
                             int nrows) {
  int r = blockIdx.x * blockDim.x + threadIdx.x;
  if (r >= nrows) return;
  const float4* q = (const float4*)(x + (size_t)r * DD);
  s[r] = __fadd_rn(pw128_sq(q), pw128_sq(q + 32));
}

// No-LDS GEMM: wave owns 8 rows (z via wave-uniform scalar loads -> SGPR
// operand in the FMA); lane owns 8 codes (codebook L2-resident, streamed
// global->VGPR, double-buffered). Zero LDS reads, zero main-loop barriers.
__global__ __launch_bounds__(256) void vq_kernel(
    const float* __restrict__ z, const float* __restrict__ cb,
    const float* __restrict__ s, const float* __restrict__ se,
    float* __restrict__ out) {
  __shared__ int best_l[32];

  const int tid = threadIdx.x;
  const int lane = tid & 63;
  const int wv = tid >> 6;                    // wave 0..3
  // wave-uniform base row of this wave's 8 rows
  const int rowbase =
      __builtin_amdgcn_readfirstlane((int)blockIdx.x * 32 + wv * 8);

  const float4* zq = (const float4*)(z + (size_t)rowbase * DD);  // uniform base
  const float4* cq = (const float4*)(cb + (size_t)(lane * 8) * DD);

  // ||e||^2 for this lane's 8 codes
  float se_reg[8];
  {
    const float4* sq = (const float4*)(se + lane * 8);
    float4 a = sq[0], b = sq[1];
    se_reg[0] = a.x; se_reg[1] = a.y; se_reg[2] = a.z; se_reg[3] = a.w;
    se_reg[4] = b.x; se_reg[5] = b.y; se_reg[6] = b.z; se_reg[7] = b.w;
  }

  float acc[8][8];
#pragma unroll
  for (int i = 0; i < 8; ++i)
#pragma unroll
    for (int j = 0; j < 8; ++j) acc[i][j] = 0.0f;

  // double-buffered e fragments (lane's 8 codes, one float4-column each)
  float4 efa[8], efb[8];
#pragma unroll
  for (int j = 0; j < 8; ++j) efa[j] = cq[j * 64];   // k4 = 0

#pragma unroll 1
  for (int k4 = 0; k4 < 64; k4 += 2) {
    // issue loads for k4+1 (fly under the efa FMA phase)
#pragma unroll
    for (int j = 0; j < 8; ++j) efb[j] = cq[j * 64 + k4 + 1];
    // phase A: z column k4 (wave-uniform scalar loads), FMA with efa
#pragma unroll
    for (int i = 0; i < 8; ++i) {
      float4 zf = zq[i * 64 + k4];
#pragma unroll
      for (int j = 0; j < 8; ++j) {
        // strict k-ascending FMA chain per (row, code) — bit-identical to ref
        acc[i][j] = __fmaf_rn(zf.x, efa[j].x, acc[i][j]);
        acc[i][j] = __fmaf_rn(zf.y, efa[j].y, acc[i][j]);
        acc[i][j] = __fmaf_rn(zf.z, efa[j].z, acc[i][j]);
        acc[i][j] = __fmaf_rn(zf.w, efa[j].w, acc[i][j]);
      }
    }
    // issue loads for k4+2 (wraps harmlessly to 0 on the final iteration)
    const int nk4 = (k4 + 2 < 64) ? (k4 + 2) : 0;
#pragma unroll
    for (int j = 0; j < 8; ++j) efa[j] = cq[j * 64 + nk4];
    // phase B: z column k4+1, FMA with efb
#pragma unroll
    for (int i = 0; i < 8; ++i) {
      float4 zf = zq[i * 64 + k4 + 1];
#pragma unroll
      for (int j = 0; j < 8; ++j) {
        acc[i][j] = __fmaf_rn(zf.x, efb[j].x, acc[i][j]);
        acc[i][j] = __fmaf_rn(zf.y, efb[j].y, acc[i][j]);
        acc[i][j] = __fmaf_rn(zf.z, efb[j].z, acc[i][j]);
        acc[i][j] = __fmaf_rn(zf.w, efb[j].w, acc[i][j]);
      }
    }
  }

  // d = (s - 2*dot) + se, rounded exactly like the reference; argmin with
  // first-index tie-break (lexicographic (d, code) min — order-independent)
#pragma unroll
  for (int i = 0; i < 8; ++i) {
    float s_r = s[rowbase + i];               // wave-uniform scalar load
    float bd = INFINITY;
    int   bi = INT_MAX;
#pragma unroll
    for (int j = 0; j < 8; ++j) {
      int code = lane * 8 + j;
      float d = __fadd_rn(__fsub_rn(s_r, __fmul_rn(2.0f, acc[i][j])),
                          se_reg[j]);
      if (d < bd || (d == bd && code < bi)) { bd = d; bi = code; }
    }
    // full-wave reduce (64 lanes)
#pragma unroll
    for (int off = 1; off < 64; off <<= 1) {
      float od = __shfl_xor(bd, off, 64);
      int   oi = __shfl_xor(bi, off, 64);
      if (od < bd || (od == bd && oi < bi)) { bd = od; bi = oi; }
    }
    if (lane == 0) best_l[wv * 8 + i] = bi;
  }
  __syncthreads();

  // epilogue: out0 = fl(z + fl(cb[idx]-z)), out1 = cb[idx]   (32 rows/block)
  const int r0 = blockIdx.x * 32;
  const float4* zg = (const float4*)z;
  const float4* cg = (const float4*)cb;
  float4* out0 = (float4*)out;
  float4* out1 = (float4*)(out + (size_t)M_ROWS * DD);
#pragma unroll
  for (int it = 0; it < 8; ++it) {
    int row = it * 4 + wv;                    // 8 iters x 4 waves = 32 rows
    int c4 = lane;                            // 64 float4 per row, coalesced
    size_t gidx = (size_t)(r0 + row) * 64 + c4;
    float4 zv = zg[gidx];
    float4 cv = cg[(size_t)best_l[row] * 64 + c4];
    float4 o0;
    o0.x = __fadd_rn(zv.x, __fsub_rn(cv.x, zv.x));
    o0.y = __fadd_rn(zv.y, __fsub_rn(cv.y, zv.y));
    o0.z = __fadd_rn(zv.z, __fsub_rn(cv.z, zv.z));
    o0.w = __fadd_rn(zv.w, __fsub_rn(cv.w, zv.w));
    out0[gidx] = o0;
    out1[gidx] = cv;
  }
}

extern "C" void kernel_launch(void* const* d_in, const int* in_sizes, int n_in,
                              void* d_out, int out_size, void* d_ws, size_t ws_size,
                              hipStream_t stream) {
  const float* z  = (const float*)d_in[0];   // [65536, 256]
  const float* cb = (const float*)d_in[1];   // [512, 256]
  float* out = (float*)d_out;                // 2 x [65536, 256] concat
  float* s  = (float*)d_ws;                  // ||z||^2 per row
  float* se = s + M_ROWS;                    // ||e||^2 per code

  sumsq_kernel<<<M_ROWS / 256, 256, 0, stream>>>(z, s, M_ROWS);
  sumsq_kernel<<<KC / 256, 256, 0, stream>>>(cb, se, KC);
  vq_kernel<<<M_ROWS / 32, 256, 0, stream>>>(z, cb, s, se, out);
}

// Round 6
// 303.103 us; speedup vs baseline: 2.5264x; 2.5264x over previous
//
#include <hip/hip_runtime.h>
#include <math.h>
#include <limits.h>

#define M_ROWS 65536   // B*N = 64*1024
#define DD     256     // feature dim
#define KC     512     // codes
#define RPW    8       // rows per wave (wave-uniform -> scalar z loads)
#define RPB    32      // rows per block (4 waves)

// numpy-style pairwise sum (8 accumulators, block 128) of squares of 128 floats.
__device__ __forceinline__ float pw128_sq(const float4* __restrict__ q) {
  float r[8];
  {
    float4 a = q[0], b = q[1];
    r[0] = __fmul_rn(a.x, a.x); r[1] = __fmul_rn(a.y, a.y);
    r[2] = __fmul_rn(a.z, a.z); r[3] = __fmul_rn(a.w, a.w);
    r[4] = __fmul_rn(b.x, b.x); r[5] = __fmul_rn(b.y, b.y);
    r[6] = __fmul_rn(b.z, b.z); r[7] = __fmul_rn(b.w, b.w);
  }
#pragma unroll
  for (int i = 2; i < 32; i += 2) {
    float4 a = q[i], b = q[i + 1];
    r[0] = __fadd_rn(r[0], __fmul_rn(a.x, a.x));
    r[1] = __fadd_rn(r[1], __fmul_rn(a.y, a.y));
    r[2] = __fadd_rn(r[2], __fmul_rn(a.z, a.z));
    r[3] = __fadd_rn(r[3], __fmul_rn(a.w, a.w));
    r[4] = __fadd_rn(r[4], __fmul_rn(b.x, b.x));
    r[5] = __fadd_rn(r[5], __fmul_rn(b.y, b.y));
    r[6] = __fadd_rn(r[6], __fmul_rn(b.z, b.z));
    r[7] = __fadd_rn(r[7], __fmul_rn(b.w, b.w));
  }
  return __fadd_rn(__fadd_rn(__fadd_rn(r[0], r[1]), __fadd_rn(r[2], r[3])),
                   __fadd_rn(__fadd_rn(r[4], r[5]), __fadd_rn(r[6], r[7])));
}

__global__ void sumsq_kernel(const float* __restrict__ x, float* __restrict__ s,
                             int nrows) {
  int r = blockIdx.x * blockDim.x + threadIdx.x;
  if (r >= nrows) return;
  const float4* q = (const float4*)(x + (size_t)r * DD);
  s[r] = __fadd_rn(pw128_sq(q), pw128_sq(q + 32));
}

// async global->LDS, 16B/lane: LDS dest = wave-uniform base + lane*16
typedef __attribute__((address_space(1))) const void gas_void;
typedef __attribute__((address_space(3))) void las_void;
__device__ __forceinline__ void gl_lds16(const void* g, void* l) {
  __builtin_amdgcn_global_load_lds((gas_void*)g, (las_void*)l, 16, 0, 0);
}

// Hybrid GEMM:
//  - z: wave-uniform rows -> scalar (SMEM) pipe, no LDS, no VALU addressing
//  - e: all 512 codes staged per k-slice (16 floats) in one 32 KB LDS buffer,
//       coalesced global_load_lds, XOR-swizzled slot q ^= (c>>1)&3 so the
//       64-lane column read is a conflict-free ds_read_b128 pattern.
//  Lane owns codes c = lane + 64*j (j=0..7); wave owns 8 rows; acc 8x8.
__global__ __launch_bounds__(256) void vq_kernel(
    const float* __restrict__ z, const float* __restrict__ cb,
    const float* __restrict__ s, const float* __restrict__ se,
    float* __restrict__ out) {
  __shared__ float4 es4[KC * 4];   // 32 KB: 512 code-rows x 4 float4, swizzled
  __shared__ int best_l[RPB];

  const int tid = threadIdx.x;
  const int lane = tid & 63;
  const int wv = tid >> 6;                    // wave 0..3
  const int rowbase =
      __builtin_amdgcn_readfirstlane((int)blockIdx.x * RPB + wv * RPW);
  const float4* zq = (const float4*)(z + (size_t)rowbase * DD);  // uniform base
  const float4* cg = (const float4*)cb;
  const int esw = (lane >> 1) & 3;            // read-side swizzle (c>>1)&3

  // ||e||^2 for this lane's 8 codes (c = lane + 64j)
  float se_reg[8];
#pragma unroll
  for (int j = 0; j < 8; ++j) se_reg[j] = se[lane + 64 * j];

  float acc[8][8];
#pragma unroll
  for (int i = 0; i < 8; ++i)
#pragma unroll
    for (int j = 0; j < 8; ++j) acc[i][j] = 0.0f;

#pragma unroll 1
  for (int ks = 0; ks < 16; ++ks) {           // 16 k-slices of 16 floats
    // stage slice: 512 codes x 4 float4 = 2048 slots; linear LDS dest,
    // inverse-swizzled global source (slot u: c=u>>2, q=(u&3)^((c>>1)&3))
#pragma unroll
    for (int seg = 0; seg < 8; ++seg) {
      int u = (wv * 8 + seg) * 64 + lane;
      int c = u >> 2;
      int q = (u & 3) ^ ((c >> 1) & 3);
      gl_lds16(&cg[(size_t)c * 64 + ks * 4 + q],
               (char*)es4 + (wv * 8 + seg) * 1024);
    }
    __syncthreads();                          // vmcnt drained -> slice visible

#pragma unroll
    for (int k4 = 0; k4 < 4; ++k4) {
      const float4* ep = &es4[lane * 4 + (k4 ^ esw)];
      float4 ef[8];
#pragma unroll
      for (int j = 0; j < 8; ++j) ef[j] = ep[j * 256];  // code lane+64j
#pragma unroll
      for (int i = 0; i < 8; ++i) {
        float4 zf = zq[(size_t)i * 64 + ks * 4 + k4];   // scalar load (uniform)
#pragma unroll
        for (int j = 0; j < 8; ++j) {
          // strict k-ascending FMA chain per (row, code) — bit-identical to ref
          acc[i][j] = __fmaf_rn(zf.x, ef[j].x, acc[i][j]);
          acc[i][j] = __fmaf_rn(zf.y, ef[j].y, acc[i][j]);
          acc[i][j] = __fmaf_rn(zf.z, ef[j].z, acc[i][j]);
          acc[i][j] = __fmaf_rn(zf.w, ef[j].w, acc[i][j]);
        }
      }
    }
    __syncthreads();                          // readers done before next stage
  }

  // d = (s - 2*dot) + se, rounded exactly like the reference; lexicographic
  // (d, code) argmin -> order-independent, first-index tie-break preserved
#pragma unroll
  for (int i = 0; i < 8; ++i) {
    float s_r = s[rowbase + i];               // wave-uniform scalar load
    float bd = INFINITY;
    int   bi = INT_MAX;
#pragma unroll
    for (int j = 0; j < 8; ++j) {
      int code = lane + 64 * j;
      float d = __fadd_rn(__fsub_rn(s_r, __fmul_rn(2.0f, acc[i][j])),
                          se_reg[j]);
      if (d < bd || (d == bd && code < bi)) { bd = d; bi = code; }
    }
#pragma unroll
    for (int off = 1; off < 64; off <<= 1) {  // full-wave reduce
      float od = __shfl_xor(bd, off, 64);
      int   oi = __shfl_xor(bi, off, 64);
      if (od < bd || (od == bd && oi < bi)) { bd = od; bi = oi; }
    }
    if (lane == 0) best_l[wv * RPW + i] = bi;
  }
  __syncthreads();

  // epilogue: out0 = fl(z + fl(cb[idx]-z)), out1 = cb[idx]   (32 rows/block)
  const int r0 = blockIdx.x * RPB;
  const float4* zg = (const float4*)z;
  float4* out0 = (float4*)out;
  float4* out1 = (float4*)(out + (size_t)M_ROWS * DD);
#pragma unroll
  for (int it = 0; it < 8; ++it) {
    int row = it * 4 + wv;                    // 8 iters x 4 waves = 32 rows
    size_t gidx = (size_t)(r0 + row) * 64 + lane;
    float4 zv = zg[gidx];
    float4 cv = cg[(size_t)best_l[row] * 64 + lane];
    float4 o0;
    o0.x = __fadd_rn(zv.x, __fsub_rn(cv.x, zv.x));
    o0.y = __fadd_rn(zv.y, __fsub_rn(cv.y, zv.y));
    o0.z = __fadd_rn(zv.z, __fsub_rn(cv.z, zv.z));
    o0.w = __fadd_rn(zv.w, __fsub_rn(cv.w, zv.w));
    out0[gidx] = o0;
    out1[gidx] = cv;
  }
}

extern "C" void kernel_launch(void* const* d_in, const int* in_sizes, int n_in,
                              void* d_out, int out_size, void* d_ws, size_t ws_size,
                              hipStream_t stream) {
  const float* z  = (const float*)d_in[0];   // [65536, 256]
  const float* cb = (const float*)d_in[1];   // [512, 256]
  float* out = (float*)d_out;                // 2 x [65536, 256] concat
  float* s  = (float*)d_ws;                  // ||z||^2 per row
  float* se = s + M_ROWS;                    // ||e||^2 per code

  sumsq_kernel<<<M_ROWS / 256, 256, 0, stream>>>(z, s, M_ROWS);
  sumsq_kernel<<<KC / 256, 256, 0, stream>>>(cb, se, KC);
  vq_kernel<<<M_ROWS / RPB, 256, 0, stream>>>(z, cb, s, se, out);
}